// Round 4
// baseline (568.264 us; speedup 1.0000x reference)
//
#include <hip/hip_runtime.h>
#include <math.h>

#define EPSF 1e-5f
#define NNC 46656

typedef __attribute__((ext_vector_type(4))) float  f32x4;
typedef __attribute__((ext_vector_type(8))) short  short8;
typedef __attribute__((ext_vector_type(8))) unsigned short ushort8;
typedef __attribute__((ext_vector_type(4))) unsigned int uint4v;

__device__ __forceinline__ float bf2f(unsigned short u) {
    unsigned int x = ((unsigned int)u) << 16;
    return __builtin_bit_cast(float, x);
}
__device__ __forceinline__ unsigned short f2bf(float f) {
    unsigned int x = __builtin_bit_cast(unsigned int, f);
    unsigned int r = (x + 0x7fffu + ((x >> 16) & 1u)) >> 16;
    return (unsigned short)r;
}

// ---- workspace layout (float offsets) ----
#define WS_PP    0u          // P' [36][1024] f32
#define WS_C1    36864u      // [1024] f32
#define WS_SH    37888u      // Sh bf16 [216][1024] (c1+P0+P1+P2) -> 110592 f
#define WS_S3    148480u     // S3 bf16 [216][1024] (P3+P4+P5)    -> 110592 f
#define WS_W2BF  259072u     // W2 bf16 [256][1024] -> 131072 f
#define WS_C2    390144u     // [256] f32
#define WS_W3BF  390400u     // W3 bf16 [784][256]  -> 100352 f
#define WS_C3    490752u     // [16] f32
#define WS_XBF   490768u     // X bf16 [64][160] -> 5120 f
#define WS_SX2   495888u     // [64] f32
#define WS_E1T   495952u     // e1n^T [256 o][64 b] f32 -> 16384 f
#define WS_E2T   512336u     // e2n^T [1024 j][64 b] f32 -> 65536 f
// total 577872 floats ~ 2.31 MB

#define OBS_SIZE (64*NNC)
#define DIST_OFF OBS_SIZE
#define LOSS_OFF (OBS_SIZE + 64*36)

// ---- decoder LDS layout (bytes) ----
// sE2p[256]f32 @0 (1024); sE2f[64]f32 @1024 (256); base 1280
// region A @1280 (32768): phase1 Albs bf16[32][64][8] | phase2/3 emL bf16[64][160](20480)
//                         + h3T waves0-1 @1280+20480=21760 (2x5120)
// region C @34048 (10240): h3T waves2-3
// region B @44288 (32768): phase1/2 h2L bf16[32][64][8] | phase3 XL bf16[64][160]
#define LDS_BYTES 77056

// ============================ K1: independent prep + encoder conv/bn ============================

__global__ void dvae_k1(const float* __restrict__ x, const float* __restrict__ conv_w,
                        const float* __restrict__ conv_b,
                        const float* __restrict__ ebn2_g, const float* __restrict__ ebn2_b,
                        const float* __restrict__ embeds, const float* __restrict__ dfc1_w,
                        const float* __restrict__ dfc1_b,
                        const float* __restrict__ dbn1_g, const float* __restrict__ dbn1_b,
                        const float* __restrict__ dbn1_rm, const float* __restrict__ dbn1_rv,
                        const float* __restrict__ dfc2_w, const float* __restrict__ dfc2_b,
                        const float* __restrict__ dbn2_g, const float* __restrict__ dbn2_b,
                        const float* __restrict__ dbn2_rm, const float* __restrict__ dbn2_rv,
                        const float* __restrict__ dct1_w, const float* __restrict__ dct1_b,
                        const float* __restrict__ dbn3_g, const float* __restrict__ dbn3_b,
                        const float* __restrict__ dbn3_rm, const float* __restrict__ dbn3_rv,
                        float* __restrict__ ws) {
    int bx = blockIdx.x, tid = threadIdx.x;
    if (bx < 144) {                      // ---- P' table + c1 ----
        int t = bx * 256 + tid;
        int vk = t >> 10, j = t & 1023;
        int v = vk / 6;
        float s1 = dbn1_g[j] * rsqrtf(dbn1_rv[j] + EPSF);
        const float* e = embeds + vk * 32;
        const float* w = dfc1_w + j * 192 + v * 32;
        float acc = 0.f;
#pragma unroll
        for (int d = 0; d < 32; ++d) acc += e[d] * w[d];
        ws[WS_PP + vk * 1024 + j] = s1 * acc;
        if (vk == 0) ws[WS_C1 + j] = s1 * dfc1_b[j] + dbn1_b[j] - dbn1_rm[j] * s1;
    } else if (bx < 400) {               // ---- W2 bf16 + c2 ----
        int t = (bx - 144) * 256 + tid;  // < 65536
        int i = t >> 8, kq = (t & 255) * 4;
        float s2 = dbn2_g[i] * rsqrtf(dbn2_rv[i] + EPSF);
        float4 w = *(const float4*)(dfc2_w + i * 1024 + kq);
        unsigned short* dst = (unsigned short*)(ws + WS_W2BF) + i * 1024 + kq;
        dst[0] = f2bf(s2 * w.x); dst[1] = f2bf(s2 * w.y);
        dst[2] = f2bf(s2 * w.z); dst[3] = f2bf(s2 * w.w);
        if (kq == 0) ws[WS_C2 + i] = s2 * dfc2_b[i] + dbn2_b[i] - dbn2_rm[i] * s2;
    } else if (bx < 1184) {              // ---- W3 bf16 + c3 ----
        int t = (bx - 400) * 256 + tid;  // < 200704
        int up = t >> 8, k = t & 255;
        int o = up & 15, hw = up >> 4;
        float s3 = dbn3_g[o] * rsqrtf(dbn3_rv[o] + EPSF);
        ((unsigned short*)(ws + WS_W3BF))[t] = f2bf(s3 * dct1_w[k * 784 + o * 49 + hw]);
        if (t < 16) {
            float s = dbn3_g[t] * rsqrtf(dbn3_rv[t] + EPSF);
            ws[WS_C3 + t] = s * dct1_b[t] + dbn3_b[t] - dbn3_rm[t] * s;
        }
    } else if (bx == 1184) {             // ---- X bf16 + sum(x^2) ----
        unsigned short* Xb = (unsigned short*)(ws + WS_XBF);
        if (tid < 64) {
            const float* xp = x + tid * 147;
            float s = 0.f;
            for (int qq = 0; qq < 147; ++qq) { float v = xp[qq]; s += v * v; }
            ws[WS_SX2 + tid] = s;
        }
        for (int e = tid; e < 64 * 160; e += 256) {
            int b = e / 160, col = e % 160;
            float v = 0.f;
            if (col < 147) { int hw = col / 3, c = col % 3; v = x[b * 147 + c * 49 + hw]; }
            Xb[e] = f2bf(v);
        }
    } else {                             // ---- encoder conv GEMM + BN-train (fused) ----
        int blk = bx - 1185;             // 0..63
        int b = tid & 63, oL = tid >> 6;
        int o = blk * 4 + oL;
        const float* xp = x + b * 147;
        const float* wp = conv_w + o * 147;
        float acc = conv_b[o];
        for (int qq = 0; qq < 147; ++qq) acc += xp[qq] * wp[qq];
        float m = acc;
#pragma unroll
        for (int s = 1; s < 64; s <<= 1) m += __shfl_xor(m, s);
        m *= (1.f / 64.f);
        float d = acc - m;
        float var = d * d;
#pragma unroll
        for (int s = 1; s < 64; s <<= 1) var += __shfl_xor(var, s);
        var *= (1.f / 64.f);
        float y = ebn2_g[o] * d * rsqrtf(var + EPSF) + ebn2_b[o];
        ws[WS_E1T + o * 64 + b] = fmaxf(y, 0.f);
    }
}

// ============================ K2: digit tables + encoder fc1/bn ============================

__global__ void dvae_k2(const float* __restrict__ fc1_w, const float* __restrict__ fc1_b,
                        const float* __restrict__ ebn1_g, const float* __restrict__ ebn1_b,
                        float* __restrict__ ws) {
    int bx = blockIdx.x, tid = threadIdx.x;
    const float* Pp = ws + WS_PP;
    if (bx < 108) {                      // Sh = c1 + P0[d0] + P1[d1] + P2[d2]
        int t = bx * 256 + tid;          // < 27648
        int gh = t >> 7, kg = (t & 127) * 8;
        int d0 = gh / 36, d1 = (gh / 6) % 6, d2 = gh % 6;
        const float* r0 = Pp + d0 * 1024 + kg;
        const float* r1 = Pp + (6 + d1) * 1024 + kg;
        const float* r2 = Pp + (12 + d2) * 1024 + kg;
        const float* cc = ws + WS_C1 + kg;
        ushort8 o;
#pragma unroll
        for (int e = 0; e < 8; ++e) o[e] = f2bf(cc[e] + r0[e] + r1[e] + r2[e]);
        *(ushort8*)((unsigned short*)(ws + WS_SH) + gh * 1024 + kg) = o;
    } else if (bx < 216) {               // S3 = P3[d3] + P4[d4] + P5[d5]
        int t = (bx - 108) * 256 + tid;
        int gl = t >> 7, kg = (t & 127) * 8;
        int d3 = gl / 36, d4 = (gl / 6) % 6, d5 = gl % 6;
        const float* r3 = Pp + (18 + d3) * 1024 + kg;
        const float* r4 = Pp + (24 + d4) * 1024 + kg;
        const float* r5 = Pp + (30 + d5) * 1024 + kg;
        ushort8 o;
#pragma unroll
        for (int e = 0; e < 8; ++e) o[e] = f2bf(r3[e] + r4[e] + r5[e]);
        *(ushort8*)((unsigned short*)(ws + WS_S3) + gl * 1024 + kg) = o;
    } else {                             // encoder fc1 GEMM + BN-train
        int blk = bx - 216;              // 0..255
        int b = tid & 63, jL = tid >> 6;
        int j = blk * 4 + jL;
        const float* e1 = ws + WS_E1T;
        const float* wp = fc1_w + j * 256;
        float acc = fc1_b[j];
        for (int o = 0; o < 256; ++o) acc += e1[o * 64 + b] * wp[o];
        float m = acc;
#pragma unroll
        for (int s = 1; s < 64; s <<= 1) m += __shfl_xor(m, s);
        m *= (1.f / 64.f);
        float d = acc - m;
        float var = d * d;
#pragma unroll
        for (int s = 1; s < 64; s <<= 1) var += __shfl_xor(var, s);
        var *= (1.f / 64.f);
        float y = ebn1_g[j] * d * rsqrtf(var + EPSF) + ebn1_b[j];
        ws[WS_E2T + j * 64 + b] = fmaxf(y, 0.f);
    }
}

// ============================ K3: fused MFMA decoder (+ encoder final in block 0) ============================

__launch_bounds__(256, 2)
__global__ void dvae_k3(const unsigned short* __restrict__ Sh,
                        const unsigned short* __restrict__ S3g,
                        const unsigned short* __restrict__ W2,
                        const float* __restrict__ c2g,
                        const unsigned short* __restrict__ W3,
                        const float* __restrict__ c3g,
                        const float* __restrict__ d2wg,
                        const float* __restrict__ d2bg,
                        const unsigned short* __restrict__ Xg,
                        const float* __restrict__ sx2g,
                        const float* __restrict__ e2T,
                        const float* __restrict__ fc2_w,
                        const float* __restrict__ fc2_b,
                        float* __restrict__ out) {
    extern __shared__ char sm[];
    int tid = threadIdx.x;

    if (blockIdx.x == 0) {
        // ---- encoder final: logits, per-v softmax, entropy ----
        float* LG = (float*)sm;          // [64][36]
        int b = tid >> 2, tq = tid & 3;
        float accv[9];
#pragma unroll
        for (int it = 0; it < 9; ++it) accv[it] = fc2_b[tq * 9 + it];
        for (int j = 0; j < 1024; ++j) {
            float ev = e2T[j * 64 + b];
#pragma unroll
            for (int it = 0; it < 9; ++it) accv[it] += ev * fc2_w[(tq * 9 + it) * 1024 + j];
        }
#pragma unroll
        for (int it = 0; it < 9; ++it) LG[b * 36 + tq * 9 + it] = accv[it];
        __syncthreads();
        if (tid < 64) {
            float loss = 0.f;
#pragma unroll
            for (int v = 0; v < 6; ++v) {
                float mx = -1e30f;
#pragma unroll
                for (int k = 0; k < 6; ++k) mx = fmaxf(mx, LG[tid * 36 + v * 6 + k]);
                float s = 0.f, ex[6];
#pragma unroll
                for (int k = 0; k < 6; ++k) { ex[k] = expf(LG[tid * 36 + v * 6 + k] - mx); s += ex[k]; }
                float inv = 1.f / s;
#pragma unroll
                for (int k = 0; k < 6; ++k) {
                    float dd = ex[k] * inv;
                    out[DIST_OFF + tid * 36 + v * 6 + k] = dd;
                    loss += dd * logf(dd + 1e-10f);
                }
            }
            out[LOSS_OFF + tid] = 0.1f * loss;
        }
        return;
    }

    // ---- decoder ----
    int wv = tid >> 6, lane = tid & 63, l15 = lane & 15, q = lane >> 4;
    int nbase = (blockIdx.x - 1) * 64;
    float* sE2p = (float*)(sm + 0);
    float* sE2f = (float*)(sm + 1024);
    unsigned short* Albs = (unsigned short*)(sm + 1280);
    unsigned short* emL  = (unsigned short*)(sm + 1280);
    float* h3w = (wv < 2) ? (float*)(sm + 21760 + wv * 5120)
                          : (float*)(sm + 34048 + (wv - 2) * 5120);
    unsigned short* h2L = (unsigned short*)(sm + 44288);
    unsigned short* XL  = (unsigned short*)(sm + 44288);

    // ---------------- phase 1: h2 = relu(h1 @ W2^T + c2) ----------------
    f32x4 acc[4][4];
#pragma unroll
    for (int a = 0; a < 4; ++a)
#pragma unroll
        for (int b = 0; b < 4; ++b) acc[a][b] = (f32x4){0.f, 0.f, 0.f, 0.f};

    int mB = tid >> 2, sub = tid & 3;
    int nm = nbase + mB;
    int gh = nm / 216;
    int r216 = nm - gh * 216;
    const unsigned short* shp = Sh + gh * 1024 + sub * 64;
    const unsigned short* s3p = S3g + r216 * 1024 + sub * 64;

    for (int kc = 0; kc < 4; ++kc) {
        __syncthreads();
        int kb = kc * 256;
        // batched loads, then packed convert (trunc pack for h1)
        ushort8 hv8[8], sv8[8];
#pragma unroll
        for (int t = 0; t < 8; ++t) {
            hv8[t] = *(const ushort8*)(shp + kb + t * 8);
            sv8[t] = *(const ushort8*)(s3p + kb + t * 8);
        }
#pragma unroll
        for (int t = 0; t < 8; ++t) {
            uint4v H = __builtin_bit_cast(uint4v, hv8[t]);
            uint4v S = __builtin_bit_cast(uint4v, sv8[t]);
            uint4v O;
#pragma unroll
            for (int d = 0; d < 4; ++d) {
                float hlo = __builtin_bit_cast(float, H[d] << 16);
                float hhi = __builtin_bit_cast(float, H[d] & 0xffff0000u);
                float slo = __builtin_bit_cast(float, S[d] << 16);
                float shi = __builtin_bit_cast(float, S[d] & 0xffff0000u);
                unsigned int rlo = __builtin_bit_cast(unsigned int, fmaxf(hlo + slo, 0.f));
                unsigned int rhi = __builtin_bit_cast(unsigned int, fmaxf(hhi + shi, 0.f));
                O[d] = (rlo >> 16) | (rhi & 0xffff0000u);
            }
            *(ushort8*)(Albs + ((sub * 8 + t) * 64 + mB) * 8) = __builtin_bit_cast(ushort8, O);
        }
        __syncthreads();
        const unsigned short* bbase = W2 + (wv * 64 + l15) * 1024 + kb + q * 8;
        short8 bpre[4];
#pragma unroll
        for (int j = 0; j < 4; ++j) bpre[j] = *(const short8*)(bbase + j * 16384);
#pragma unroll
        for (int s = 0; s < 8; ++s) {
            short8 bcur[4];
#pragma unroll
            for (int j = 0; j < 4; ++j) bcur[j] = bpre[j];
            if (s < 7) {
#pragma unroll
                for (int j = 0; j < 4; ++j)
                    bpre[j] = *(const short8*)(bbase + j * 16384 + (s + 1) * 32);
            }
            short8 af[4];
#pragma unroll
            for (int mt = 0; mt < 4; ++mt)
                af[mt] = *(const short8*)(Albs + ((s * 4 + q) * 64 + mt * 16 + l15) * 8);
#pragma unroll
            for (int mt = 0; mt < 4; ++mt)
#pragma unroll
                for (int j = 0; j < 4; ++j)
                    acc[mt][j] = __builtin_amdgcn_mfma_f32_16x16x32_bf16(af[mt], bcur[j], acc[mt][j], 0, 0, 0);
        }
    }
    // h2 epilogue (RNE) -> h2L bf16 [i>>3][m][i&7]
#pragma unroll
    for (int j = 0; j < 4; ++j) {
        int i = wv * 64 + j * 16 + l15;
        float cc = c2g[i];
#pragma unroll
        for (int mt = 0; mt < 4; ++mt)
#pragma unroll
            for (int r = 0; r < 4; ++r) {
                int m = mt * 16 + q * 4 + r;
                h2L[((i >> 3) * 64 + m) * 8 + (i & 7)] = f2bf(fmaxf(acc[mt][j][r] + cc, 0.f));
            }
    }
    __syncthreads();

    // ---------------- phase 2: GEMM3 + channel projection ----------------
    float c3v = c3g[l15];
    float db0 = d2bg[0], db1 = d2bg[1], db2 = d2bg[2];
    float dw0[16], dw1[16], dw2[16];
#pragma unroll
    for (int o = 0; o < 16; ++o) {
        dw0[o] = d2wg[o * 3 + 0]; dw1[o] = d2wg[o * 3 + 1]; dw2[o] = d2wg[o * 3 + 2];
    }
    float sE2a = 0.f;
    for (int c = wv; c < 13; c += 4) {
        int hw0 = c * 4;
        f32x4 a2[4][4];
#pragma unroll
        for (int a = 0; a < 4; ++a)
#pragma unroll
            for (int b = 0; b < 4; ++b) a2[a][b] = (f32x4){0.f, 0.f, 0.f, 0.f};
        const unsigned short* b3[4];
#pragma unroll
        for (int j = 0; j < 4; ++j) {
            int hw = hw0 + j; if (hw > 48) hw = 48;
            b3[j] = W3 + (hw * 16 + l15) * 256 + q * 8;
        }
        short8 bpre[4];
#pragma unroll
        for (int j = 0; j < 4; ++j) bpre[j] = *(const short8*)(b3[j]);
#pragma unroll
        for (int s = 0; s < 8; ++s) {
            short8 bcur[4];
#pragma unroll
            for (int j = 0; j < 4; ++j) bcur[j] = bpre[j];
            if (s < 7) {
#pragma unroll
                for (int j = 0; j < 4; ++j) bpre[j] = *(const short8*)(b3[j] + (s + 1) * 32);
            }
            short8 af[4];
#pragma unroll
            for (int mt = 0; mt < 4; ++mt)
                af[mt] = *(const short8*)(h2L + ((s * 4 + q) * 64 + mt * 16 + l15) * 8);
#pragma unroll
            for (int mt = 0; mt < 4; ++mt)
#pragma unroll
                for (int j = 0; j < 4; ++j)
                    a2[mt][j] = __builtin_amdgcn_mfma_f32_16x16x32_bf16(af[mt], bcur[j], a2[mt][j], 0, 0, 0);
        }
        // per-hw epilogue: h3 -> h3w [m][o] (stride 20), then em per m=lane
#pragma unroll
        for (int j = 0; j < 4; ++j) {
            int hw = hw0 + j;
            if (hw <= 48) {
#pragma unroll
                for (int mt = 0; mt < 4; ++mt)
#pragma unroll
                    for (int r = 0; r < 4; ++r)
                        h3w[(mt * 16 + q * 4 + r) * 20 + l15] = fmaxf(a2[mt][j][r] + c3v, 0.f);
                float hvv[16];
#pragma unroll
                for (int g = 0; g < 4; ++g) {
                    f32x4 tv = *(const f32x4*)(h3w + lane * 20 + g * 4);
                    hvv[g * 4 + 0] = tv[0]; hvv[g * 4 + 1] = tv[1];
                    hvv[g * 4 + 2] = tv[2]; hvv[g * 4 + 3] = tv[3];
                }
                float e0 = db0, e1 = db1, e2 = db2;
#pragma unroll
                for (int o = 0; o < 16; ++o) {
                    e0 += hvv[o] * dw0[o]; e1 += hvv[o] * dw1[o]; e2 += hvv[o] * dw2[o];
                }
                unsigned short u0 = f2bf(e0), u1 = f2bf(e1), u2 = f2bf(e2);
                float f0 = bf2f(u0), f1 = bf2f(u1), f2v = bf2f(u2);
                sE2a += f0 * f0 + f1 * f1 + f2v * f2v;
                emL[lane * 160 + hw * 3 + 0] = u0;
                emL[lane * 160 + hw * 3 + 1] = u1;
                emL[lane * 160 + hw * 3 + 2] = u2;
            }
        }
    }
    sE2p[wv * 64 + lane] = sE2a;
    __syncthreads();

    // finalize sE2, zero em tail cols, stage X over h2 region
    if (tid < 64) sE2f[tid] = sE2p[tid] + sE2p[64 + tid] + sE2p[128 + tid] + sE2p[192 + tid];
    for (int e = tid; e < 64 * 13; e += 256) emL[(e / 13) * 160 + 147 + (e % 13)] = 0;
    for (int e = tid; e < 1280; e += 256)
        *(ushort8*)(XL + e * 8) = *(const ushort8*)(Xg + e * 8);
    __syncthreads();

    // ---------------- phase 3: obs = X @ em^T ----------------
    f32x4 aO[4];
#pragma unroll
    for (int j = 0; j < 4; ++j) aO[j] = (f32x4){0.f, 0.f, 0.f, 0.f};
    const unsigned short* xrow = XL + (wv * 16 + l15) * 160 + q * 8;
#pragma unroll
    for (int s = 0; s < 5; ++s) {
        short8 af = *(const short8*)(xrow + s * 32);
#pragma unroll
        for (int j = 0; j < 4; ++j) {
            short8 bfv = *(const short8*)(emL + (j * 16 + l15) * 160 + s * 32 + q * 8);
            aO[j] = __builtin_amdgcn_mfma_f32_16x16x32_bf16(af, bfv, aO[j], 0, 0, 0);
        }
    }
    int b0 = wv * 16 + q * 4;
    float sxv[4];
#pragma unroll
    for (int r = 0; r < 4; ++r) sxv[r] = sx2g[b0 + r];
#pragma unroll
    for (int j = 0; j < 4; ++j) {
        int n = nbase + j * 16 + l15;
        float he = 0.5f * sE2f[j * 16 + l15];
#pragma unroll
        for (int r = 0; r < 4; ++r)
            out[(size_t)(b0 + r) * NNC + n] = aO[j][r] - he - 0.5f * sxv[r];
    }
}

// ============================ launcher ============================

extern "C" void kernel_launch(void* const* d_in, const int* in_sizes, int n_in,
                              void* d_out, int out_size, void* d_ws, size_t ws_size,
                              hipStream_t stream) {
    const float* x       = (const float*)d_in[0];
    const float* conv_w  = (const float*)d_in[1];
    const float* conv_b  = (const float*)d_in[2];
    const float* ebn2_g  = (const float*)d_in[3];
    const float* ebn2_b  = (const float*)d_in[4];
    const float* fc1_w   = (const float*)d_in[5];
    const float* fc1_b   = (const float*)d_in[6];
    const float* ebn1_g  = (const float*)d_in[7];
    const float* ebn1_b  = (const float*)d_in[8];
    const float* fc2_w   = (const float*)d_in[9];
    const float* fc2_b   = (const float*)d_in[10];
    const float* embeds  = (const float*)d_in[11];
    const float* dfc1_w  = (const float*)d_in[12];
    const float* dfc1_b  = (const float*)d_in[13];
    const float* dbn1_g  = (const float*)d_in[14];
    const float* dbn1_b  = (const float*)d_in[15];
    const float* dbn1_rm = (const float*)d_in[16];
    const float* dbn1_rv = (const float*)d_in[17];
    const float* dfc2_w  = (const float*)d_in[18];
    const float* dfc2_b  = (const float*)d_in[19];
    const float* dbn2_g  = (const float*)d_in[20];
    const float* dbn2_b  = (const float*)d_in[21];
    const float* dbn2_rm = (const float*)d_in[22];
    const float* dbn2_rv = (const float*)d_in[23];
    const float* dct1_w  = (const float*)d_in[24];
    const float* dct1_b  = (const float*)d_in[25];
    const float* dbn3_g  = (const float*)d_in[26];
    const float* dbn3_b  = (const float*)d_in[27];
    const float* dbn3_rm = (const float*)d_in[28];
    const float* dbn3_rv = (const float*)d_in[29];
    const float* dct2_w  = (const float*)d_in[30];
    const float* dct2_b  = (const float*)d_in[31];

    float* ws  = (float*)d_ws;
    float* out = (float*)d_out;

    dvae_k1<<<1249, 256, 0, stream>>>(x, conv_w, conv_b, ebn2_g, ebn2_b,
                                      embeds, dfc1_w, dfc1_b, dbn1_g, dbn1_b, dbn1_rm, dbn1_rv,
                                      dfc2_w, dfc2_b, dbn2_g, dbn2_b, dbn2_rm, dbn2_rv,
                                      dct1_w, dct1_b, dbn3_g, dbn3_b, dbn3_rm, dbn3_rv, ws);
    dvae_k2<<<472, 256, 0, stream>>>(fc1_w, fc1_b, ebn1_g, ebn1_b, ws);

    hipFuncSetAttribute(reinterpret_cast<const void*>(dvae_k3),
                        hipFuncAttributeMaxDynamicSharedMemorySize, LDS_BYTES);
    dvae_k3<<<730, 256, LDS_BYTES, stream>>>(
        (const unsigned short*)(ws + WS_SH), (const unsigned short*)(ws + WS_S3),
        (const unsigned short*)(ws + WS_W2BF), ws + WS_C2,
        (const unsigned short*)(ws + WS_W3BF), ws + WS_C3,
        dct2_w, dct2_b,
        (const unsigned short*)(ws + WS_XBF), ws + WS_SX2,
        ws + WS_E2T, fc2_w, fc2_b, out);
}

// Round 5
// 317.149 us; speedup vs baseline: 1.7918x; 1.7918x over previous
//
#include <hip/hip_runtime.h>
#include <math.h>

#define EPSF 1e-5f
#define NNC 46656

typedef __attribute__((ext_vector_type(4))) float  f32x4;
typedef __attribute__((ext_vector_type(8))) short  short8;
typedef __attribute__((ext_vector_type(8))) unsigned short ushort8;
typedef __attribute__((ext_vector_type(4))) unsigned int uint4v;

__device__ __forceinline__ float bf2f(unsigned short u) {
    unsigned int x = ((unsigned int)u) << 16;
    return __builtin_bit_cast(float, x);
}
__device__ __forceinline__ unsigned short f2bf(float f) {
    unsigned int x = __builtin_bit_cast(unsigned int, f);
    unsigned int r = (x + 0x7fffu + ((x >> 16) & 1u)) >> 16;
    return (unsigned short)r;
}

// ---- workspace layout (float offsets) ----
#define WS_SH    37888u      // Sh bf16 [216][1024] (c1+P0+P1+P2) -> 110592 f
#define WS_S3    148480u     // S3 bf16 [216][1024] (P3+P4+P5)    -> 110592 f
#define WS_W2BF  259072u     // W2 bf16 [256][1024] -> 131072 f
#define WS_C2    390144u     // [256] f32
#define WS_W3BF  390400u     // W3 bf16 [784][256]  -> 100352 f
#define WS_C3    490752u     // [16] f32
#define WS_XBF   490768u     // X bf16 [64][160] -> 5120 f
#define WS_SX2   495888u     // [64] f32
#define WS_E1T   495952u     // e1n^T [256 o][64 b] f32 -> 16384 f
#define WS_E2T   512336u     // e2n^T [1024 j][64 b] f32 -> 65536 f

#define OBS_SIZE (64*NNC)
#define DIST_OFF OBS_SIZE
#define LOSS_OFF (OBS_SIZE + 64*36)

// decoder LDS (same as R4): sE2p@0, sE2f@1024, Albs/emL@1280, h3w@21760/34048, h2L/XL@44288
#define LDS_BYTES 77056

// ============================ K1: ALL prep + encoder conv/bn ============================
// blocks: [0,216) Sh | [216,432) S3 | [432,688) W2 | [688,1472) W3 | 1472 X | [1473,1537) conv

__global__ void dvae_k1(const float* __restrict__ x, const float* __restrict__ conv_w,
                        const float* __restrict__ conv_b,
                        const float* __restrict__ ebn2_g, const float* __restrict__ ebn2_b,
                        const float* __restrict__ embeds, const float* __restrict__ dfc1_w,
                        const float* __restrict__ dfc1_b,
                        const float* __restrict__ dbn1_g, const float* __restrict__ dbn1_b,
                        const float* __restrict__ dbn1_rm, const float* __restrict__ dbn1_rv,
                        const float* __restrict__ dfc2_w, const float* __restrict__ dfc2_b,
                        const float* __restrict__ dbn2_g, const float* __restrict__ dbn2_b,
                        const float* __restrict__ dbn2_rm, const float* __restrict__ dbn2_rv,
                        const float* __restrict__ dct1_w, const float* __restrict__ dct1_b,
                        const float* __restrict__ dbn3_g, const float* __restrict__ dbn3_b,
                        const float* __restrict__ dbn3_rm, const float* __restrict__ dbn3_rv,
                        float* __restrict__ ws) {
    __shared__ float se[96];
    int bx = blockIdx.x, tid = threadIdx.x;
    if (bx < 216) {                      // ---- Sh row: c1 + s1*(dot0+dot1+dot2+b1) ----
        int gh = bx;
        int d0 = gh / 36, d1 = (gh / 6) % 6, d2 = gh % 6;
        if (tid < 32) {
            se[tid]      = embeds[d0 * 32 + tid];
            se[32 + tid] = embeds[(6 + d1) * 32 + tid];
            se[64 + tid] = embeds[(12 + d2) * 32 + tid];
        }
        __syncthreads();
        unsigned short* Sh = (unsigned short*)(ws + WS_SH);
#pragma unroll
        for (int jj = 0; jj < 4; ++jj) {
            int j = jj * 256 + tid;
            const float* w = dfc1_w + j * 192;
            float dot = 0.f;
#pragma unroll
            for (int qv = 0; qv < 24; ++qv) {
                float4 wv4 = *(const float4*)(w + qv * 4);
                dot += wv4.x * se[qv * 4] + wv4.y * se[qv * 4 + 1]
                     + wv4.z * se[qv * 4 + 2] + wv4.w * se[qv * 4 + 3];
            }
            float s1 = dbn1_g[j] * rsqrtf(dbn1_rv[j] + EPSF);
            float val = s1 * (dot + dfc1_b[j]) + dbn1_b[j] - dbn1_rm[j] * s1;
            Sh[gh * 1024 + j] = f2bf(val);
        }
    } else if (bx < 432) {               // ---- S3 row: s1*(dot3+dot4+dot5) ----
        int gl = bx - 216;
        int d3 = gl / 36, d4 = (gl / 6) % 6, d5 = gl % 6;
        if (tid < 32) {
            se[tid]      = embeds[(18 + d3) * 32 + tid];
            se[32 + tid] = embeds[(24 + d4) * 32 + tid];
            se[64 + tid] = embeds[(30 + d5) * 32 + tid];
        }
        __syncthreads();
        unsigned short* S3 = (unsigned short*)(ws + WS_S3);
#pragma unroll
        for (int jj = 0; jj < 4; ++jj) {
            int j = jj * 256 + tid;
            const float* w = dfc1_w + j * 192 + 96;
            float dot = 0.f;
#pragma unroll
            for (int qv = 0; qv < 24; ++qv) {
                float4 wv4 = *(const float4*)(w + qv * 4);
                dot += wv4.x * se[qv * 4] + wv4.y * se[qv * 4 + 1]
                     + wv4.z * se[qv * 4 + 2] + wv4.w * se[qv * 4 + 3];
            }
            float s1 = dbn1_g[j] * rsqrtf(dbn1_rv[j] + EPSF);
            S3[gl * 1024 + j] = f2bf(s1 * dot);
        }
    } else if (bx < 688) {               // ---- W2 bf16 + c2 ----
        int t = (bx - 432) * 256 + tid;  // < 65536
        int i = t >> 8, kq = (t & 255) * 4;
        float s2 = dbn2_g[i] * rsqrtf(dbn2_rv[i] + EPSF);
        float4 w = *(const float4*)(dfc2_w + i * 1024 + kq);
        unsigned short* dst = (unsigned short*)(ws + WS_W2BF) + i * 1024 + kq;
        dst[0] = f2bf(s2 * w.x); dst[1] = f2bf(s2 * w.y);
        dst[2] = f2bf(s2 * w.z); dst[3] = f2bf(s2 * w.w);
        if (kq == 0) ws[WS_C2 + i] = s2 * dfc2_b[i] + dbn2_b[i] - dbn2_rm[i] * s2;
    } else if (bx < 1472) {              // ---- W3 bf16 + c3 ----
        int t = (bx - 688) * 256 + tid;  // < 200704
        int up = t >> 8, k = t & 255;
        int o = up & 15, hw = up >> 4;
        float s3 = dbn3_g[o] * rsqrtf(dbn3_rv[o] + EPSF);
        ((unsigned short*)(ws + WS_W3BF))[t] = f2bf(s3 * dct1_w[k * 784 + o * 49 + hw]);
        if (t < 16) {
            float s = dbn3_g[t] * rsqrtf(dbn3_rv[t] + EPSF);
            ws[WS_C3 + t] = s * dct1_b[t] + dbn3_b[t] - dbn3_rm[t] * s;
        }
    } else if (bx == 1472) {             // ---- X bf16 + sum(x^2) ----
        unsigned short* Xb = (unsigned short*)(ws + WS_XBF);
        if (tid < 64) {
            const float* xp = x + tid * 147;
            float s = 0.f;
            for (int qq = 0; qq < 147; ++qq) { float v = xp[qq]; s += v * v; }
            ws[WS_SX2 + tid] = s;
        }
        for (int e = tid; e < 64 * 160; e += 256) {
            int b = e / 160, col = e % 160;
            float v = 0.f;
            if (col < 147) { int hw = col / 3, c = col % 3; v = x[b * 147 + c * 49 + hw]; }
            Xb[e] = f2bf(v);
        }
    } else {                             // ---- encoder conv GEMM + BN-train ----
        int blk = bx - 1473;             // 0..63
        int b = tid & 63, oL = tid >> 6;
        int o = blk * 4 + oL;
        const float* xp = x + b * 147;
        const float* wp = conv_w + o * 147;
        float acc = conv_b[o];
        for (int qq = 0; qq < 147; ++qq) acc += xp[qq] * wp[qq];
        float m = acc;
#pragma unroll
        for (int s = 1; s < 64; s <<= 1) m += __shfl_xor(m, s);
        m *= (1.f / 64.f);
        float d = acc - m;
        float var = d * d;
#pragma unroll
        for (int s = 1; s < 64; s <<= 1) var += __shfl_xor(var, s);
        var *= (1.f / 64.f);
        float y = ebn2_g[o] * d * rsqrtf(var + EPSF) + ebn2_b[o];
        ws[WS_E1T + o * 64 + b] = fmaxf(y, 0.f);
    }
}

// ============================ K2: encoder fc1 + BN ============================

__global__ void dvae_k2(const float* __restrict__ fc1_w, const float* __restrict__ fc1_b,
                        const float* __restrict__ ebn1_g, const float* __restrict__ ebn1_b,
                        float* __restrict__ ws) {
    int blk = blockIdx.x, tid = threadIdx.x;
    int b = tid & 63, jL = tid >> 6;
    int j = blk * 4 + jL;
    const float* e1 = ws + WS_E1T;
    const float* wp = fc1_w + j * 256;
    float acc = fc1_b[j];
    for (int o = 0; o < 256; ++o) acc += e1[o * 64 + b] * wp[o];
    float m = acc;
#pragma unroll
    for (int s = 1; s < 64; s <<= 1) m += __shfl_xor(m, s);
    m *= (1.f / 64.f);
    float d = acc - m;
    float var = d * d;
#pragma unroll
    for (int s = 1; s < 64; s <<= 1) var += __shfl_xor(var, s);
    var *= (1.f / 64.f);
    float y = ebn1_g[j] * d * rsqrtf(var + EPSF) + ebn1_b[j];
    ws[WS_E2T + j * 64 + b] = fmaxf(y, 0.f);
}

// ============================ K3: fused MFMA decoder + logits block ============================

__launch_bounds__(256, 2)
__global__ void dvae_k3(const unsigned short* __restrict__ Sh,
                        const unsigned short* __restrict__ S3g,
                        const unsigned short* __restrict__ W2,
                        const float* __restrict__ c2g,
                        const unsigned short* __restrict__ W3,
                        const float* __restrict__ c3g,
                        const float* __restrict__ d2wg,
                        const float* __restrict__ d2bg,
                        const unsigned short* __restrict__ Xg,
                        const float* __restrict__ sx2g,
                        const float* __restrict__ e2T,
                        const float* __restrict__ fc2_w,
                        const float* __restrict__ fc2_b,
                        float* __restrict__ out) {
    extern __shared__ char sm[];
    int tid = threadIdx.x;

    if (blockIdx.x == 0) {
        // ---- encoder final: logits via LDS-staged chunks, softmax, entropy ----
        float* wch = (float*)sm;              // [36][128]
        float* ech = (float*)(sm + 18432);    // [128][64]
        float* LG  = (float*)(sm + 51200);    // [64][36]
        int b = tid & 63;
        int wvU = __builtin_amdgcn_readfirstlane(tid >> 6);
        float accv[9];
#pragma unroll
        for (int it = 0; it < 9; ++it) accv[it] = 0.f;
        for (int ch = 0; ch < 8; ++ch) {
            __syncthreads();
            for (int e = tid; e < 36 * 128; e += 256) {
                int o = e >> 7, jl = e & 127;
                wch[e] = fc2_w[o * 1024 + ch * 128 + jl];
            }
            for (int e = tid; e < 128 * 64; e += 256)
                ech[e] = e2T[(ch * 128 + (e >> 6)) * 64 + (e & 63)];
            __syncthreads();
            for (int jl = 0; jl < 128; ++jl) {
                float ev = ech[jl * 64 + b];
#pragma unroll
                for (int it = 0; it < 9; ++it)
                    accv[it] += ev * wch[(wvU + it * 4) * 128 + jl];
            }
        }
#pragma unroll
        for (int it = 0; it < 9; ++it) {
            int o = wvU + it * 4;
            LG[b * 36 + o] = accv[it] + fc2_b[o];
        }
        __syncthreads();
        if (tid < 64) {
            float loss = 0.f;
#pragma unroll
            for (int v = 0; v < 6; ++v) {
                float mx = -1e30f;
#pragma unroll
                for (int k = 0; k < 6; ++k) mx = fmaxf(mx, LG[tid * 36 + v * 6 + k]);
                float s = 0.f, ex[6];
#pragma unroll
                for (int k = 0; k < 6; ++k) { ex[k] = expf(LG[tid * 36 + v * 6 + k] - mx); s += ex[k]; }
                float inv = 1.f / s;
#pragma unroll
                for (int k = 0; k < 6; ++k) {
                    float dd = ex[k] * inv;
                    out[DIST_OFF + tid * 36 + v * 6 + k] = dd;
                    loss += dd * logf(dd + 1e-10f);
                }
            }
            out[LOSS_OFF + tid] = 0.1f * loss;
        }
        return;
    }

    // ---- decoder ----
    int wv = tid >> 6, lane = tid & 63, l15 = lane & 15, q = lane >> 4;
    int nbase = (blockIdx.x - 1) * 64;
    float* sE2p = (float*)(sm + 0);
    float* sE2f = (float*)(sm + 1024);
    unsigned short* Albs = (unsigned short*)(sm + 1280);
    unsigned short* emL  = (unsigned short*)(sm + 1280);
    float* h3w = (wv < 2) ? (float*)(sm + 21760 + wv * 5120)
                          : (float*)(sm + 34048 + (wv - 2) * 5120);
    unsigned short* h2L = (unsigned short*)(sm + 44288);
    unsigned short* XL  = (unsigned short*)(sm + 44288);

    // ---------------- phase 1: h2 = relu(h1 @ W2^T + c2) ----------------
    f32x4 acc[4][4];
#pragma unroll
    for (int a = 0; a < 4; ++a)
#pragma unroll
        for (int b = 0; b < 4; ++b) acc[a][b] = (f32x4){0.f, 0.f, 0.f, 0.f};

    int mB = tid >> 2, sub = tid & 3;
    int nm = nbase + mB;
    int gh = nm / 216;
    int r216 = nm - gh * 216;
    const unsigned short* shp = Sh + gh * 1024 + sub * 64;
    const unsigned short* s3p = S3g + r216 * 1024 + sub * 64;

    for (int kc = 0; kc < 4; ++kc) {
        __syncthreads();
        int kb = kc * 256;
        ushort8 hv8[8], sv8[8];
#pragma unroll
        for (int t = 0; t < 8; ++t) {
            hv8[t] = *(const ushort8*)(shp + kb + t * 8);
            sv8[t] = *(const ushort8*)(s3p + kb + t * 8);
        }
#pragma unroll
        for (int t = 0; t < 8; ++t) {
            uint4v H = __builtin_bit_cast(uint4v, hv8[t]);
            uint4v S = __builtin_bit_cast(uint4v, sv8[t]);
            uint4v O;
#pragma unroll
            for (int d = 0; d < 4; ++d) {
                float hlo = __builtin_bit_cast(float, H[d] << 16);
                float hhi = __builtin_bit_cast(float, H[d] & 0xffff0000u);
                float slo = __builtin_bit_cast(float, S[d] << 16);
                float shi = __builtin_bit_cast(float, S[d] & 0xffff0000u);
                unsigned int rlo = __builtin_bit_cast(unsigned int, fmaxf(hlo + slo, 0.f));
                unsigned int rhi = __builtin_bit_cast(unsigned int, fmaxf(hhi + shi, 0.f));
                O[d] = (rlo >> 16) | (rhi & 0xffff0000u);
            }
            *(ushort8*)(Albs + ((sub * 8 + t) * 64 + mB) * 8) = __builtin_bit_cast(ushort8, O);
        }
        __syncthreads();
        const unsigned short* bbase = W2 + (wv * 64 + l15) * 1024 + kb + q * 8;
        short8 bpre[4];
#pragma unroll
        for (int j = 0; j < 4; ++j) bpre[j] = *(const short8*)(bbase + j * 16384);
#pragma unroll
        for (int s = 0; s < 8; ++s) {
            short8 bcur[4];
#pragma unroll
            for (int j = 0; j < 4; ++j) bcur[j] = bpre[j];
            if (s < 7) {
#pragma unroll
                for (int j = 0; j < 4; ++j)
                    bpre[j] = *(const short8*)(bbase + j * 16384 + (s + 1) * 32);
            }
            short8 af[4];
#pragma unroll
            for (int mt = 0; mt < 4; ++mt)
                af[mt] = *(const short8*)(Albs + ((s * 4 + q) * 64 + mt * 16 + l15) * 8);
#pragma unroll
            for (int mt = 0; mt < 4; ++mt)
#pragma unroll
                for (int j = 0; j < 4; ++j)
                    acc[mt][j] = __builtin_amdgcn_mfma_f32_16x16x32_bf16(af[mt], bcur[j], acc[mt][j], 0, 0, 0);
        }
    }
#pragma unroll
    for (int j = 0; j < 4; ++j) {
        int i = wv * 64 + j * 16 + l15;
        float cc = c2g[i];
#pragma unroll
        for (int mt = 0; mt < 4; ++mt)
#pragma unroll
            for (int r = 0; r < 4; ++r) {
                int m = mt * 16 + q * 4 + r;
                h2L[((i >> 3) * 64 + m) * 8 + (i & 7)] = f2bf(fmaxf(acc[mt][j][r] + cc, 0.f));
            }
    }
    __syncthreads();

    // ---------------- phase 2: GEMM3 + channel projection ----------------
    float c3v = c3g[l15];
    float db0 = d2bg[0], db1 = d2bg[1], db2 = d2bg[2];
    float dw0[16], dw1[16], dw2[16];
#pragma unroll
    for (int o = 0; o < 16; ++o) {
        dw0[o] = d2wg[o * 3 + 0]; dw1[o] = d2wg[o * 3 + 1]; dw2[o] = d2wg[o * 3 + 2];
    }
    float sE2a = 0.f;
    for (int c = wv; c < 13; c += 4) {
        int hw0 = c * 4;
        f32x4 a2[4][4];
#pragma unroll
        for (int a = 0; a < 4; ++a)
#pragma unroll
            for (int b = 0; b < 4; ++b) a2[a][b] = (f32x4){0.f, 0.f, 0.f, 0.f};
        const unsigned short* b3[4];
#pragma unroll
        for (int j = 0; j < 4; ++j) {
            int hw = hw0 + j; if (hw > 48) hw = 48;
            b3[j] = W3 + (hw * 16 + l15) * 256 + q * 8;
        }
        short8 bpre[4];
#pragma unroll
        for (int j = 0; j < 4; ++j) bpre[j] = *(const short8*)(b3[j]);
#pragma unroll
        for (int s = 0; s < 8; ++s) {
            short8 bcur[4];
#pragma unroll
            for (int j = 0; j < 4; ++j) bcur[j] = bpre[j];
            if (s < 7) {
#pragma unroll
                for (int j = 0; j < 4; ++j) bpre[j] = *(const short8*)(b3[j] + (s + 1) * 32);
            }
            short8 af[4];
#pragma unroll
            for (int mt = 0; mt < 4; ++mt)
                af[mt] = *(const short8*)(h2L + ((s * 4 + q) * 64 + mt * 16 + l15) * 8);
#pragma unroll
            for (int mt = 0; mt < 4; ++mt)
#pragma unroll
                for (int j = 0; j < 4; ++j)
                    a2[mt][j] = __builtin_amdgcn_mfma_f32_16x16x32_bf16(af[mt], bcur[j], a2[mt][j], 0, 0, 0);
        }
#pragma unroll
        for (int j = 0; j < 4; ++j) {
            int hw = hw0 + j;
            if (hw <= 48) {
#pragma unroll
                for (int mt = 0; mt < 4; ++mt)
#pragma unroll
                    for (int r = 0; r < 4; ++r)
                        h3w[(mt * 16 + q * 4 + r) * 20 + l15] = fmaxf(a2[mt][j][r] + c3v, 0.f);
                float hvv[16];
#pragma unroll
                for (int g = 0; g < 4; ++g) {
                    f32x4 tv = *(const f32x4*)(h3w + lane * 20 + g * 4);
                    hvv[g * 4 + 0] = tv[0]; hvv[g * 4 + 1] = tv[1];
                    hvv[g * 4 + 2] = tv[2]; hvv[g * 4 + 3] = tv[3];
                }
                float e0 = db0, e1 = db1, e2 = db2;
#pragma unroll
                for (int o = 0; o < 16; ++o) {
                    e0 += hvv[o] * dw0[o]; e1 += hvv[o] * dw1[o]; e2 += hvv[o] * dw2[o];
                }
                unsigned short u0 = f2bf(e0), u1 = f2bf(e1), u2 = f2bf(e2);
                float f0 = bf2f(u0), f1 = bf2f(u1), f2v = bf2f(u2);
                sE2a += f0 * f0 + f1 * f1 + f2v * f2v;
                emL[lane * 160 + hw * 3 + 0] = u0;
                emL[lane * 160 + hw * 3 + 1] = u1;
                emL[lane * 160 + hw * 3 + 2] = u2;
            }
        }
    }
    sE2p[wv * 64 + lane] = sE2a;
    __syncthreads();

    if (tid < 64) sE2f[tid] = sE2p[tid] + sE2p[64 + tid] + sE2p[128 + tid] + sE2p[192 + tid];
    for (int e = tid; e < 64 * 13; e += 256) emL[(e / 13) * 160 + 147 + (e % 13)] = 0;
    for (int e = tid; e < 1280; e += 256)
        *(ushort8*)(XL + e * 8) = *(const ushort8*)(Xg + e * 8);
    __syncthreads();

    // ---------------- phase 3: obs = X @ em^T ----------------
    f32x4 aO[4];
#pragma unroll
    for (int j = 0; j < 4; ++j) aO[j] = (f32x4){0.f, 0.f, 0.f, 0.f};
    const unsigned short* xrow = XL + (wv * 16 + l15) * 160 + q * 8;
#pragma unroll
    for (int s = 0; s < 5; ++s) {
        short8 af = *(const short8*)(xrow + s * 32);
#pragma unroll
        for (int j = 0; j < 4; ++j) {
            short8 bfv = *(const short8*)(emL + (j * 16 + l15) * 160 + s * 32 + q * 8);
            aO[j] = __builtin_amdgcn_mfma_f32_16x16x32_bf16(af, bfv, aO[j], 0, 0, 0);
        }
    }
    int b0 = wv * 16 + q * 4;
    float sxv[4];
#pragma unroll
    for (int r = 0; r < 4; ++r) sxv[r] = sx2g[b0 + r];
#pragma unroll
    for (int j = 0; j < 4; ++j) {
        int n = nbase + j * 16 + l15;
        float he = 0.5f * sE2f[j * 16 + l15];
#pragma unroll
        for (int r = 0; r < 4; ++r)
            out[(size_t)(b0 + r) * NNC + n] = aO[j][r] - he - 0.5f * sxv[r];
    }
}

// ============================ launcher ============================

extern "C" void kernel_launch(void* const* d_in, const int* in_sizes, int n_in,
                              void* d_out, int out_size, void* d_ws, size_t ws_size,
                              hipStream_t stream) {
    const float* x       = (const float*)d_in[0];
    const float* conv_w  = (const float*)d_in[1];
    const float* conv_b  = (const float*)d_in[2];
    const float* ebn2_g  = (const float*)d_in[3];
    const float* ebn2_b  = (const float*)d_in[4];
    const float* fc1_w   = (const float*)d_in[5];
    const float* fc1_b   = (const float*)d_in[6];
    const float* ebn1_g  = (const float*)d_in[7];
    const float* ebn1_b  = (const float*)d_in[8];
    const float* fc2_w   = (const float*)d_in[9];
    const float* fc2_b   = (const float*)d_in[10];
    const float* embeds  = (const float*)d_in[11];
    const float* dfc1_w  = (const float*)d_in[12];
    const float* dfc1_b  = (const float*)d_in[13];
    const float* dbn1_g  = (const float*)d_in[14];
    const float* dbn1_b  = (const float*)d_in[15];
    const float* dbn1_rm = (const float*)d_in[16];
    const float* dbn1_rv = (const float*)d_in[17];
    const float* dfc2_w  = (const float*)d_in[18];
    const float* dfc2_b  = (const float*)d_in[19];
    const float* dbn2_g  = (const float*)d_in[20];
    const float* dbn2_b  = (const float*)d_in[21];
    const float* dbn2_rm = (const float*)d_in[22];
    const float* dbn2_rv = (const float*)d_in[23];
    const float* dct1_w  = (const float*)d_in[24];
    const float* dct1_b  = (const float*)d_in[25];
    const float* dbn3_g  = (const float*)d_in[26];
    const float* dbn3_b  = (const float*)d_in[27];
    const float* dbn3_rm = (const float*)d_in[28];
    const float* dbn3_rv = (const float*)d_in[29];
    const float* dct2_w  = (const float*)d_in[30];
    const float* dct2_b  = (const float*)d_in[31];

    float* ws  = (float*)d_ws;
    float* out = (float*)d_out;

    dvae_k1<<<1537, 256, 0, stream>>>(x, conv_w, conv_b, ebn2_g, ebn2_b,
                                      embeds, dfc1_w, dfc1_b, dbn1_g, dbn1_b, dbn1_rm, dbn1_rv,
                                      dfc2_w, dfc2_b, dbn2_g, dbn2_b, dbn2_rm, dbn2_rv,
                                      dct1_w, dct1_b, dbn3_g, dbn3_b, dbn3_rm, dbn3_rv, ws);
    dvae_k2<<<256, 256, 0, stream>>>(fc1_w, fc1_b, ebn1_g, ebn1_b, ws);

    hipFuncSetAttribute(reinterpret_cast<const void*>(dvae_k3),
                        hipFuncAttributeMaxDynamicSharedMemorySize, LDS_BYTES);
    dvae_k3<<<730, 256, LDS_BYTES, stream>>>(
        (const unsigned short*)(ws + WS_SH), (const unsigned short*)(ws + WS_S3),
        (const unsigned short*)(ws + WS_W2BF), ws + WS_C2,
        (const unsigned short*)(ws + WS_W3BF), ws + WS_C3,
        dct2_w, dct2_b,
        (const unsigned short*)(ws + WS_XBF), ws + WS_SX2,
        ws + WS_E2T, fc2_w, fc2_b, out);
}